// Round 10
// baseline (208.182 us; speedup 1.0000x reference)
//
#include <hip/hip_runtime.h>
#include <hip/hip_bf16.h>
#include <cstddef>

// GCN forward: out = A·(relu(A·(X·W1)+b1))·W2 + b2
// NFEAT=512, NHID=128, NCLS=40 hard-wired; N,E from in_sizes.
// CSR (counting sort) -> segment-sum SpMM (multi-edge-per-wave gathers).
// gemm1: whole pre-swizzled W1T in LDS, 512-thr block (8 waves, VGPR budget 256),
// explicit 4-deep A-register prefetch -> guaranteed in-flight HBM stream.

typedef float f32x4 __attribute__((ext_vector_type(4)));
typedef short bf16x8 __attribute__((ext_vector_type(8)));

static __device__ __forceinline__ short f2bf(float f) {
    __hip_bfloat16 b = __float2bfloat16(f);
    return *reinterpret_cast<short*>(&b);
}
static __device__ __forceinline__ float bflo(unsigned u) {
    union { unsigned i; float f; } v; v.i = u << 16; return v.f;
}
static __device__ __forceinline__ float bfhi(unsigned u) {
    union { unsigned i; float f; } v; v.i = u & 0xFFFF0000u; return v.f;
}
static __device__ __forceinline__ unsigned pack2bf(float lo, float hi) {
    unsigned a = (unsigned short)f2bf(lo);
    unsigned b = (unsigned short)f2bf(hi);
    return a | (b << 16);
}

typedef const __attribute__((address_space(1))) void* gas_ptr;
typedef __attribute__((address_space(3))) void* las_ptr;
static __device__ __forceinline__ void gload16(const void* g, void* l) {
    __builtin_amdgcn_global_load_lds((gas_ptr)g, (las_ptr)l, 16, 0, 0);
}

// ---- prep: W1->W1Ts (swizzled bf16 W1T), W2->W2Ts, zero cur[] ----
__global__ __launch_bounds__(256) void prep_kernel(
    const float* __restrict__ W1, short* __restrict__ W1Ts,
    const float* __restrict__ W2, short* __restrict__ W2Ts,
    int* __restrict__ cur, int N)
{
    int idx = blockIdx.x * 256 + threadIdx.x;
    if (idx < 65536) {
        int k = idx >> 7, n = idx & 127;
        int lin = n * 512 + k;
        W1Ts[lin ^ ((n & 7) << 3)] = f2bf(W1[idx]);
    } else if (idx < 65536 + 6144) {
        int i2 = idx - 65536;
        int n = i2 >> 7, k = i2 & 127;
        W2Ts[i2 ^ ((n & 7) << 3)] = (n < 40) ? f2bf(W2[k * 40 + n]) : (short)0;
    } else if (idx < 65536 + 6144 + N) {
        cur[idx - 65536 - 6144] = 0;
    }
}

// ---------------- GEMM1: XW1b[M,128](bf16) = X[M,512](f32) @ W1 ----------------
// 512 thr = 8 waves: 4 row-groups x 2 col-halves; wave = 32r x 64c (2x4 frags).
// Whole W1Ts in LDS (128KB, 1 block/CU). Explicit 4-deep A prefetch in registers.
__global__ __launch_bounds__(512, 2) void gemm1_mfma_kernel(
    const float* __restrict__ X, const short* __restrict__ W1Ts,
    short* __restrict__ XW1b, int M)
{
    __shared__ __align__(16) short Bs[128 * 512];   // 128 KB, pre-swizzled

    const int tid = threadIdx.x;
    const int w   = tid >> 6;          // 0..7
    const int l   = tid & 63;
    const int l15 = l & 15;
    const int l4  = l >> 4;
    const int row0 = blockIdx.x * 128 + (w >> 1) * 32;
    const int col0 = (w & 1) * 64;

    // linear 128KB copy global->LDS (layout already swizzled in global)
    {
        const char* src = (const char*)W1Ts;
        char* dst = (char*)Bs;
#pragma unroll
        for (int i = 0; i < 16; ++i)
            gload16(src + i * 8192 + tid * 16, dst + i * 8192 + tid * 16);
    }

    const int r0 = row0 + l15,      c0 = r0 < M ? r0 : M - 1;
    const int r1 = row0 + 16 + l15, c1 = r1 < M ? r1 : M - 1;
    const float* a0p = X + (size_t)c0 * 512 + l4 * 8;
    const float* a1p = X + (size_t)c1 * 512 + l4 * 8;
    const int swz = (l15 & 7) << 3;

    // explicit 4-deep prefetch ring (statically indexed under full unroll)
    float4 p00[4], p01[4], p10[4], p11[4];
#pragma unroll
    for (int d = 0; d < 4; ++d) {
        p00[d] = *(const float4*)(a0p + d * 32);
        p01[d] = *(const float4*)(a0p + d * 32 + 4);
        p10[d] = *(const float4*)(a1p + d * 32);
        p11[d] = *(const float4*)(a1p + d * 32 + 4);
    }

    f32x4 acc[2][4];
#pragma unroll
    for (int i = 0; i < 2; ++i)
#pragma unroll
        for (int f = 0; f < 4; ++f) acc[i][f] = (f32x4)0.f;

    __syncthreads();

#pragma unroll
    for (int kt = 0; kt < 16; ++kt) {
        const int s = kt & 3;
        const float4 x00 = p00[s], x01 = p01[s];
        const float4 x10 = p10[s], x11 = p11[s];
        if (kt < 12) {
            p00[s] = *(const float4*)(a0p + (kt + 4) * 32);
            p01[s] = *(const float4*)(a0p + (kt + 4) * 32 + 4);
            p10[s] = *(const float4*)(a1p + (kt + 4) * 32);
            p11[s] = *(const float4*)(a1p + (kt + 4) * 32 + 4);
        }

        bf16x8 a0, a1;
        a0[0]=f2bf(x00.x); a0[1]=f2bf(x00.y); a0[2]=f2bf(x00.z); a0[3]=f2bf(x00.w);
        a0[4]=f2bf(x01.x); a0[5]=f2bf(x01.y); a0[6]=f2bf(x01.z); a0[7]=f2bf(x01.w);
        a1[0]=f2bf(x10.x); a1[1]=f2bf(x10.y); a1[2]=f2bf(x10.z); a1[3]=f2bf(x10.w);
        a1[4]=f2bf(x11.x); a1[5]=f2bf(x11.y); a1[6]=f2bf(x11.z); a1[7]=f2bf(x11.w);

#pragma unroll
        for (int f = 0; f < 4; ++f) {
            const int si = ((col0 + f * 16 + l15) * 512 + kt * 32 + l4 * 8) ^ swz;
            const bf16x8 b = *(const bf16x8*)&Bs[si];
            acc[0][f] = __builtin_amdgcn_mfma_f32_16x16x32_bf16(a0, b, acc[0][f], 0, 0, 0);
            acc[1][f] = __builtin_amdgcn_mfma_f32_16x16x32_bf16(a1, b, acc[1][f], 0, 0, 0);
        }
    }

    // D layout: col = lane&15, row = (lane>>4)*4 + reg
#pragma unroll
    for (int i = 0; i < 2; ++i)
#pragma unroll
        for (int r = 0; r < 4; ++r) {
            const int row = row0 + i * 16 + l4 * 4 + r;
            if (row < M) {
#pragma unroll
                for (int f = 0; f < 4; ++f)
                    XW1b[(size_t)row * 128 + col0 + f * 16 + l15] = f2bf(acc[i][f][r]);
            }
        }
}

// ---------------- CSR build ----------------
__global__ __launch_bounds__(256) void hist_kernel(const int* __restrict__ row,
                                                   int* __restrict__ counts, int E)
{
    int e = blockIdx.x * 256 + threadIdx.x;
    if (e < E) atomicAdd(&counts[row[e]], 1);
}

__global__ __launch_bounds__(256) void scan1_kernel(const int* __restrict__ counts,
                                                    int* __restrict__ excl,
                                                    int* __restrict__ bsum, int N)
{
    __shared__ int s[256];
    const int t = threadIdx.x;
    const int i = blockIdx.x * 256 + t;
    int v = (i < N) ? counts[i] : 0;
    s[t] = v; __syncthreads();
#pragma unroll
    for (int off = 1; off < 256; off <<= 1) {
        int tmp = (t >= off) ? s[t - off] : 0;
        __syncthreads();
        s[t] += tmp;
        __syncthreads();
    }
    if (i < N) excl[i] = s[t] - v;
    if (t == 255) bsum[blockIdx.x] = s[255];
}

__global__ __launch_bounds__(256) void scan2_kernel(int* __restrict__ bsum, int NB)
{
    __shared__ int s[256];
    const int t = threadIdx.x;
    int v = (t < NB) ? bsum[t] : 0;
    s[t] = v; __syncthreads();
#pragma unroll
    for (int off = 1; off < 256; off <<= 1) {
        int tmp = (t >= off) ? s[t - off] : 0;
        __syncthreads();
        s[t] += tmp;
        __syncthreads();
    }
    if (t < NB) bsum[t] = s[t] - v;
}

__global__ __launch_bounds__(256) void scan3_kernel(int* __restrict__ rowptr,
                                                    const int* __restrict__ bsum,
                                                    int* __restrict__ cur, int N, int E)
{
    int i = blockIdx.x * 256 + threadIdx.x;
    if (i < N) {
        int v = rowptr[i] + bsum[blockIdx.x];
        rowptr[i] = v;
        cur[i] = v;
    }
    if (i == 0) rowptr[N] = E;
}

__global__ __launch_bounds__(256) void sortedges_kernel(
    const int* __restrict__ row, const int* __restrict__ col,
    const float* __restrict__ w, int* __restrict__ cur,
    int2* __restrict__ se, int E)
{
    int e = blockIdx.x * 256 + threadIdx.x;
    if (e < E) {
        int r = row[e];
        int pos = atomicAdd(&cur[r], 1);
        se[pos] = make_int2(col[e], __float_as_int(w[e]));
    }
}

// ---- segment1: hb[r] = bf16(relu(b1 + sum_j w_j * xw1b[col_j])) ----
__global__ __launch_bounds__(256) void segment1_kernel(
    const int* __restrict__ rowptr, const int2* __restrict__ se,
    const uint2* __restrict__ x2, const float* __restrict__ b1,
    uint2* __restrict__ hb, int N)
{
    const int w    = threadIdx.x >> 6;
    const int lane = threadIdx.x & 63;
    const int h    = lane >> 5;          // half: which edge of the pair
    const int q    = lane & 31;          // uint2 index in row (feats 4q..4q+3)
    const int r = blockIdx.x * 4 + w;
    if (r >= N) return;

    float4 acc = make_float4(0.f, 0.f, 0.f, 0.f);
    if (h == 0) acc = *(const float4*)(b1 + 4 * q);

    int j = rowptr[r];
    const int end = rowptr[r + 1];
    for (; j + 3 < end; j += 4) {
        const int2 ea = se[j + h];
        const int2 eb = se[j + 2 + h];
        const uint2 ua = x2[(size_t)ea.x * 32 + q];
        const uint2 ub = x2[(size_t)eb.x * 32 + q];
        const float wa = __int_as_float(ea.y), wb = __int_as_float(eb.y);
        acc.x = fmaf(wa, bflo(ua.x), acc.x); acc.y = fmaf(wa, bfhi(ua.x), acc.y);
        acc.z = fmaf(wa, bflo(ua.y), acc.z); acc.w = fmaf(wa, bfhi(ua.y), acc.w);
        acc.x = fmaf(wb, bflo(ub.x), acc.x); acc.y = fmaf(wb, bfhi(ub.x), acc.y);
        acc.z = fmaf(wb, bflo(ub.y), acc.z); acc.w = fmaf(wb, bfhi(ub.y), acc.w);
    }
    for (; j < end; j += 2) {
        const int idx = j + h;
        const int ic  = idx < end ? idx : end - 1;
        const int2 e  = se[ic];
        const float wt = idx < end ? __int_as_float(e.y) : 0.f;
        const uint2 u = x2[(size_t)e.x * 32 + q];
        acc.x = fmaf(wt, bflo(u.x), acc.x); acc.y = fmaf(wt, bfhi(u.x), acc.y);
        acc.z = fmaf(wt, bflo(u.y), acc.z); acc.w = fmaf(wt, bfhi(u.y), acc.w);
    }
    acc.x += __shfl_xor(acc.x, 32);
    acc.y += __shfl_xor(acc.y, 32);
    acc.z += __shfl_xor(acc.z, 32);
    acc.w += __shfl_xor(acc.w, 32);
    if (h == 0) {
        const unsigned p0 = pack2bf(fmaxf(acc.x, 0.f), fmaxf(acc.y, 0.f));
        const unsigned p1 = pack2bf(fmaxf(acc.z, 0.f), fmaxf(acc.w, 0.f));
        hb[(size_t)r * 32 + q] = make_uint2(p0, p1);
    }
}

// ---------------- GEMM2: Yb[M,40](bf16) = hb[M,128](bf16) @ W2 ----------------
__global__ __launch_bounds__(256) void gemm2_mfma_kernel(
    const short* __restrict__ hb, const short* __restrict__ W2Ts,
    unsigned short* __restrict__ Yb, int M)
{
    __shared__ __align__(16) short Ws[48 * 128];   // 12 KB, pre-swizzled

    const int tid = threadIdx.x;
    const int w   = tid >> 6;
    const int l   = tid & 63;
    const int l15 = l & 15;
    const int l4  = l >> 4;
    const int row0 = blockIdx.x * 64 + w * 16;

    {
        const char* src = (const char*)W2Ts;
        char* dst = (char*)Ws;
#pragma unroll
        for (int i = 0; i < 3; ++i)
            gload16(src + i * 4096 + tid * 16, dst + i * 4096 + tid * 16);
    }
    __syncthreads();

    f32x4 acc[3];
#pragma unroll
    for (int f = 0; f < 3; ++f) acc[f] = (f32x4)0.f;

    const int rr = row0 + l15;
    const int cr = rr < M ? rr : M - 1;
    const short* hp = hb + (size_t)cr * 128 + l4 * 8;
    const int swz = (l15 & 7) << 3;

#pragma unroll
    for (int kt = 0; kt < 4; ++kt) {
        const bf16x8 a = *(const bf16x8*)(hp + kt * 32);
#pragma unroll
        for (int f = 0; f < 3; ++f) {
            const int si = ((f * 16 + l15) * 128 + kt * 32 + l4 * 8) ^ swz;
            const bf16x8 b = *(const bf16x8*)&Ws[si];
            acc[f] = __builtin_amdgcn_mfma_f32_16x16x32_bf16(a, b, acc[f], 0, 0, 0);
        }
    }

#pragma unroll
    for (int r = 0; r < 4; ++r) {
        const int row = row0 + l4 * 4 + r;
        if (row < M) {
#pragma unroll
            for (int f = 0; f < 3; ++f) {
                const int col = f * 16 + l15;
                if (col < 40)
                    Yb[(size_t)row * 40 + col] = (unsigned short)f2bf(acc[f][r]);
            }
        }
    }
}

// ---- segment2: out[r] = b2 + sum_j w_j * hw2b[col_j]  (3 edges/wave, x2 unroll) ----
__global__ __launch_bounds__(256) void segment2_kernel(
    const int* __restrict__ rowptr, const int2* __restrict__ se,
    const unsigned* __restrict__ hw2, const float* __restrict__ b2,
    float* __restrict__ out, int N)
{
    const int w    = threadIdx.x >> 6;
    const int lane = threadIdx.x & 63;
    const int s    = lane < 20 ? 0 : (lane < 40 ? 1 : 2);
    const int fl   = lane - s * 20;          // 0..19 (lanes 60-63 discarded)
    const int r = blockIdx.x * 4 + w;
    if (r >= N) return;

    float a0 = 0.f, a1 = 0.f;
    if (lane < 20) { float2 bb = *(const float2*)(b2 + 2 * fl); a0 = bb.x; a1 = bb.y; }

    int j = rowptr[r];
    const int end = rowptr[r + 1];
    for (; j + 5 < end; j += 6) {
        const int2 ea = se[j + s];
        const int2 eb = se[j + 3 + s];
        const unsigned ua = hw2[(size_t)ea.x * 20 + fl];
        const unsigned ub = hw2[(size_t)eb.x * 20 + fl];
        const float wa = __int_as_float(ea.y), wb = __int_as_float(eb.y);
        a0 = fmaf(wa, bflo(ua), a0); a1 = fmaf(wa, bfhi(ua), a1);
        a0 = fmaf(wb, bflo(ub), a0); a1 = fmaf(wb, bfhi(ub), a1);
    }
    for (; j < end; j += 3) {
        const int idx = j + s;
        const int ic  = idx < end ? idx : end - 1;
        const int2 e  = se[ic];
        const float wt = idx < end ? __int_as_float(e.y) : 0.f;
        const unsigned u = hw2[(size_t)e.x * 20 + fl];
        a0 = fmaf(wt, bflo(u), a0); a1 = fmaf(wt, bfhi(u), a1);
    }
    const float t0 = __shfl(a0, lane + 20);
    const float t1 = __shfl(a1, lane + 20);
    const float u0 = __shfl(a0, lane + 40);
    const float u1 = __shfl(a1, lane + 40);
    if (lane < 20)
        *(float2*)(out + (size_t)r * 40 + 2 * fl) = make_float2(a0 + t0 + u0, a1 + t1 + u1);
}

extern "C" void kernel_launch(void* const* d_in, const int* in_sizes, int n_in,
                              void* d_out, int out_size, void* d_ws, size_t ws_size,
                              hipStream_t stream)
{
    const float* x  = (const float*)d_in[0];
    const int* erow = (const int*)d_in[1];
    const int* ecol = (const int*)d_in[2];
    const float* ew = (const float*)d_in[3];
    const float* w1 = (const float*)d_in[4];
    const float* b1 = (const float*)d_in[5];
    const float* w2 = (const float*)d_in[6];
    const float* b2 = (const float*)d_in[7];
    float* out = (float*)d_out;

    const int N = in_sizes[0] / 512;   // 50000
    const int E = in_sizes[1];         // 800000
    const int NB = (N + 255) / 256;    // 196 (<=256 for scan2)

    // workspace layout (16B-aligned segments)
    short* w1ts = (short*)d_ws;                      // 128*512 bf16 (swizzled)
    short* w2ts = w1ts + 65536;                      // 48*128 bf16 (swizzled, +pad)
    short* xw1b = w2ts + 8192;                       // N*128 bf16
    short* hb   = xw1b + (size_t)N * 128;            // N*128 bf16 (relu'd)
    int* rowptr = (int*)(hb + (size_t)N * 128);      // N+1
    int* cur    = rowptr + (N + 1);                  // N
    int* bsum   = cur + N;                           // 256 (+pad to 8B align)
    int2* se    = (int2*)(bsum + 256 + ((N + 1) & 1)); // E packed edges
    short* hw2b = xw1b;                              // N*40 bf16 (reuse)

    // prep (weights + zero cur) and CSR build
    prep_kernel<<<(65536 + 6144 + N + 255) / 256, 256, 0, stream>>>(w1, w1ts, w2, w2ts, cur, N);
    hist_kernel<<<(E + 255) / 256, 256, 0, stream>>>(erow, cur, E);
    scan1_kernel<<<NB, 256, 0, stream>>>(cur, rowptr, bsum, N);
    scan2_kernel<<<1, 256, 0, stream>>>(bsum, NB);
    scan3_kernel<<<NB, 256, 0, stream>>>(rowptr, bsum, cur, N, E);
    sortedges_kernel<<<(E + 255) / 256, 256, 0, stream>>>(erow, ecol, ew, cur, se, E);

    // layer 1
    gemm1_mfma_kernel<<<(N + 127) / 128, 512, 0, stream>>>(x, w1ts, xw1b, N);
    segment1_kernel<<<(N + 3) / 4, 256, 0, stream>>>(rowptr, se,
                                                     (const uint2*)xw1b, b1,
                                                     (uint2*)hb, N);

    // layer 2
    gemm2_mfma_kernel<<<(N + 63) / 64, 256, 0, stream>>>(hb, w2ts,
                                                         (unsigned short*)hw2b, N);
    segment2_kernel<<<(N + 3) / 4, 256, 0, stream>>>(rowptr, se,
                                                     (const unsigned*)hw2b, b2, out, N);
}